// Round 7
// baseline (138.461 us; speedup 1.0000x reference)
//
#include <hip/hip_runtime.h>

#define Bv 256
#define Tv 200
#define Cv 40
#define H1v 512
#define H2v 256
#define Ov 12
#define THv 1.0f

typedef unsigned long long u64;
typedef _Float16 f16x2 __attribute__((ext_vector_type(2)));   // fdot2 operand type
typedef __fp16   g16x2 __attribute__((ext_vector_type(2)));   // cvt_pkrtz result type

#if defined(__has_builtin)
#if __has_builtin(__builtin_amdgcn_fdot2)
#define HAVE_FDOT2 1
#endif
#endif

// pack two fp32 -> u32 of two f16 (RTZ)
static __device__ __forceinline__ unsigned pkrtz(float a, float b) {
    union { g16x2 h; unsigned u; } cv;
    cv.h = __builtin_amdgcn_cvt_pkrtz(a, b);
    return cv.u;
}
static __device__ __forceinline__ f16x2 u2h(unsigned u) {
    union { unsigned u; f16x2 h; } cv; cv.u = u; return cv.h;
}
// c += dot(a,b) with fp32 accumulate
static __device__ __forceinline__ float dot2acc(unsigned a, unsigned b, float c) {
#ifdef HAVE_FDOT2
    return __builtin_amdgcn_fdot2(u2h(a), u2h(b), c, false);   // v_dot2_f32_f16
#else
    const f16x2 ah = u2h(a), bh = u2h(b);
    return c + (float)ah.x * (float)bh.x + (float)ah.y * (float)bh.y;
#endif
}

// ---------------------------------------------------------------------------
// One block per batch element, 512 threads (8 waves).
//
// PHASE 1 (speculative, barrier-free): waves 0-1 (128 threads), 4 hidden
// units/thread. R5 post-mortem: the allocator refuses to keep 160 fp32 weight
// VGPRs live (capped ~116; launch_bounds min is permission, not command) ->
// weights demoted to scratch. Fix: f16. Weights packed f16 in 80 u32 VGPRs,
// x ALSO staged as f16 in LDS (5 ds_read_b128/step -> LDS floor ~120cy/step),
// dot via v_dot2_f32_f16 (fp32 accumulate).
//
// Gate soundness for ANY input: per-dot error <= 40*xmax*wmax*2^-8 + 1e-5
// (covers RTZ input rounding, product, fp32 accum); EMA is convex, so
// |v_hat - v_exact| <= err. Fast path iff err < 0.25 && vmax < 1 - err;
// NaN/Inf fail the comparisons -> exact path. PHASE 2 = verbatim R1
// harness-verified fp32 kernel reading the untouched fp32 LDS copy.
// ---------------------------------------------------------------------------
__global__ __launch_bounds__(512, 2) void snn_main(
    const float* __restrict__ x,
    const float* __restrict__ W1,
    const float* __restrict__ Wrec,
    const float* __restrict__ W2,
    const float* __restrict__ Wout,
    const float* __restrict__ alpha1, const float* __restrict__ rho1, const float* __restrict__ ba1,
    const float* __restrict__ alpha2, const float* __restrict__ rho2, const float* __restrict__ ba2,
    const float* __restrict__ beta_out,
    float* __restrict__ out)
{
    __shared__ __align__(16) float    lds_x [Tv * Cv];   // 32000 B fp32 (phase 2)
    __shared__ __align__(16) unsigned lds_xh[Tv * Cv / 2]; // 16000 B packed f16 (phase 1)
    __shared__ __align__(16) u64 s_m1[2][8];
    __shared__ __align__(16) u64 s_m2[2][4];
    __shared__ __align__(16) u64 s_red[8];
    __shared__ float s_xmax[8];

    const int b    = blockIdx.x;
    const int tid  = threadIdx.x;
    const int lane = tid & 63;
    const int wid  = tid >> 6;

    // --- stage x: fp32 copy + packed-f16 copy + block max|x| ---
    float xm = 0.f;
    {
        const float4* xg = (const float4*)(x + (size_t)b * (Tv * Cv));
        for (int i = tid; i < (Tv * Cv) / 4; i += 512) {
            const float4 v = xg[i];
            ((float4*)lds_x)[i] = v;
            uint2 pk;
            pk.x = pkrtz(v.x, v.y);
            pk.y = pkrtz(v.z, v.w);
            ((uint2*)lds_xh)[i] = pk;
            xm = fmaxf(xm, fmaxf(fmaxf(fabsf(v.x), fabsf(v.y)),
                                 fmaxf(fabsf(v.z), fabsf(v.w))));
        }
        #pragma unroll
        for (int o = 32; o > 0; o >>= 1) xm = fmaxf(xm, __shfl_xor(xm, o));
        if (lane == 0) s_xmax[wid] = xm;
    }
    __syncthreads();

    // ================= PHASE 1: 2-wave f16 speculative scan =================
    bool bad = false;
    if (tid < 128) {
        float xmax = s_xmax[0];
        #pragma unroll
        for (int i = 1; i < 8; ++i) xmax = fmaxf(xmax, s_xmax[i]);

        // 4 W1 rows -> packed f16 in 80 u32 regs; track max|w|
        unsigned w[4][20];
        float wmax = 0.f;
        #pragma unroll
        for (int u = 0; u < 4; ++u) {
            const float4* p = (const float4*)(W1 + (tid + 128 * u) * Cv);
            #pragma unroll
            for (int i = 0; i < 10; ++i) {
                const float4 q = p[i];
                wmax = fmaxf(wmax, fmaxf(fmaxf(fabsf(q.x), fabsf(q.y)),
                                         fmaxf(fabsf(q.z), fabsf(q.w))));
                w[u][2*i]   = pkrtz(q.x, q.y);
                w[u][2*i+1] = pkrtz(q.z, q.w);
            }
        }
        const float a0 = alpha1[tid],       k0 = 1.f - a0;
        const float a1 = alpha1[tid + 128], k1 = 1.f - a1;
        const float a2 = alpha1[tid + 256], k2 = 1.f - a2;
        const float a3 = alpha1[tid + 384], k3 = 1.f - a3;
        float v0 = 0.f, v1 = 0.f, v2 = 0.f, v3 = 0.f, vmax = 0.f;

        for (int t = 0; t < Tv; ++t) {
            const uint4* xr = (const uint4*)(lds_xh + t * (Cv / 2)); // 80 B row, 16B-aligned
            const uint4 q0 = xr[0], q1 = xr[1], q2 = xr[2], q3 = xr[3], q4 = xr[4];
            unsigned xh[20] = { q0.x, q0.y, q0.z, q0.w,
                                q1.x, q1.y, q1.z, q1.w,
                                q2.x, q2.y, q2.z, q2.w,
                                q3.x, q3.y, q3.z, q3.w,
                                q4.x, q4.y, q4.z, q4.w };

            float d0, d1, d2, d3;
            {
                float ce = 0.f, co = 0.f;
                #pragma unroll
                for (int i = 0; i < 20; i += 2) { ce = dot2acc(xh[i], w[0][i], ce); co = dot2acc(xh[i+1], w[0][i+1], co); }
                d0 = ce + co;
            }
            {
                float ce = 0.f, co = 0.f;
                #pragma unroll
                for (int i = 0; i < 20; i += 2) { ce = dot2acc(xh[i], w[1][i], ce); co = dot2acc(xh[i+1], w[1][i+1], co); }
                d1 = ce + co;
            }
            {
                float ce = 0.f, co = 0.f;
                #pragma unroll
                for (int i = 0; i < 20; i += 2) { ce = dot2acc(xh[i], w[2][i], ce); co = dot2acc(xh[i+1], w[2][i+1], co); }
                d2 = ce + co;
            }
            {
                float ce = 0.f, co = 0.f;
                #pragma unroll
                for (int i = 0; i < 20; i += 2) { ce = dot2acc(xh[i], w[3][i], ce); co = dot2acc(xh[i+1], w[3][i+1], co); }
                d3 = ce + co;
            }
            v0 = a0 * v0 + k0 * d0;
            v1 = a1 * v1 + k1 * d1;
            v2 = a2 * v2 + k2 * d2;
            v3 = a3 * v3 + k3 * d3;
            vmax = fmaxf(vmax, fmaxf(fmaxf(v0, v1), fmaxf(v2, v3)));
        }

        // conservative f16 error bound; NaN/Inf fail the comparisons -> exact path
        const float err = 40.f * xmax * wmax * (1.f / 256.f) + 1e-5f;
        bad = !((err < 0.25f) && (vmax < 1.0f - err));
    }

    {
        const u64 bal = __ballot(bad);          // waves 2-7 contribute 0
        if (lane == 0) s_red[wid] = bal;
        __syncthreads();
        u64 any = 0ull;
        #pragma unroll
        for (int i = 0; i < 8; ++i) any |= s_red[i];
        if (any == 0ull) {
            // Provably spike-free: every downstream signal is exactly zero.
            if (tid < Ov) out[b * Ov + tid] = 0.f;
            return;
        }
    }

    // ================= PHASE 2: exact coupled simulation (rare) ===============
    // Verbatim R1 harness-verified pipelined kernel; fp32 lds_x untouched.
    float4 w1r[10];
    {
        const float4* p = (const float4*)(W1 + tid * Cv);
        #pragma unroll
        for (int i = 0; i < 10; ++i) w1r[i] = p[i];
    }
    const float al1 = alpha1[tid];
    const float rh1 = rho1[tid], bb1 = ba1[tid];
    float v1 = 0.f, a1 = 0.f, spk1 = 0.f;
    float al2 = 0.f, rh2 = 0.f, bb2 = 0.f, v2 = 0.f, a2 = 0.f;
    if (tid < H2v) { al2 = alpha2[tid]; rh2 = rho2[tid]; bb2 = ba2[tid]; }
    const float beta = beta_out[0];
    float vout = 0.f, osum = 0.f;

    if (tid < 8) { s_m1[0][tid] = 0ull; s_m1[1][tid] = 0ull; }
    if (tid < 4) { s_m2[0][tid] = 0ull; s_m2[1][tid] = 0ull; }
    __syncthreads();

    for (int t = 0; t < Tv + 2; ++t) {
        const int cur = t & 1, prev = cur ^ 1;

        u64 m1[8];
        #pragma unroll
        for (int i = 0; i < 8; ++i) m1[i] = s_m1[prev][i];
        u64 anyw = 0;
        #pragma unroll
        for (int i = 0; i < 8; ++i) anyw |= m1[i];
        const bool any1 = (anyw != 0ull);

        const bool doOut = (tid < Ov) & (t >= 2);
        u64 m2[4] = {0ull, 0ull, 0ull, 0ull};
        if (doOut) {
            #pragma unroll
            for (int i = 0; i < 4; ++i) m2[i] = s_m2[prev][i];
        }

        // ---- L1 update for step t ----
        if (t < Tv) {
            const float4* xr = (const float4*)(&lds_x[t * Cv]);
            float c0 = 0.f, c1 = 0.f, c2 = 0.f, c3 = 0.f;
            #pragma unroll
            for (int i = 0; i < 10; ++i) {
                const float4 xv = xr[i];
                c0 += xv.x * w1r[i].x;
                c1 += xv.y * w1r[i].y;
                c2 += xv.z * w1r[i].z;
                c3 += xv.w * w1r[i].w;
            }
            float acc = (c0 + c1) + (c2 + c3);
            if (any1) {
                #pragma unroll
                for (int w = 0; w < 8; ++w) {
                    u64 m = m1[w];
                    while (m) {
                        const int j = (w << 6) + __builtin_ctzll(m);
                        m &= (m - 1);
                        acc += Wrec[tid * H1v + j];
                    }
                }
            }
            v1 = al1 * (v1 - spk1 * THv) + (1.f - al1) * (acc - a1);
            const bool sp = (v1 >= THv);
            spk1 = sp ? 1.f : 0.f;
            a1 = rh1 * a1 + bb1 * spk1;
            const u64 bal = __ballot(sp);
            if (lane == 0) s_m1[cur][tid >> 6] = bal;
        }

        // ---- L2 update for step t-1 ----
        if ((tid < H2v) & (t >= 1) & (t <= Tv)) {
            float acc2 = 0.f;
            if (any1) {
                #pragma unroll
                for (int w = 0; w < 8; ++w) {
                    u64 m = m1[w];
                    while (m) {
                        const int j = (w << 6) + __builtin_ctzll(m);
                        m &= (m - 1);
                        acc2 += W2[tid * H1v + j];
                    }
                }
            }
            v2 = al2 * v2 + (1.f - al2) * (acc2 - a2);
            const bool sp2 = (v2 >= THv);
            a2 = rh2 * a2 + bb2 * (sp2 ? 1.f : 0.f);
            const u64 bal2 = __ballot(sp2);
            if (lane == 0) s_m2[cur][tid >> 6] = bal2;
        }

        // ---- Out update for step t-2 ----
        if (doOut) {
            float io = 0.f;
            if (m2[0] | m2[1] | m2[2] | m2[3]) {
                #pragma unroll
                for (int w = 0; w < 4; ++w) {
                    u64 m = m2[w];
                    while (m) {
                        const int j = (w << 6) + __builtin_ctzll(m);
                        m &= (m - 1);
                        io += Wout[tid * H2v + j];
                    }
                }
            }
            vout = beta * vout + (1.f - beta) * io;
            osum += vout;
        }

        __syncthreads();
    }

    if (tid < Ov) out[b * Ov + tid] = osum / (float)Tv;
}

extern "C" void kernel_launch(void* const* d_in, const int* in_sizes, int n_in,
                              void* d_out, int out_size, void* d_ws, size_t ws_size,
                              hipStream_t stream)
{
    const float* x       = (const float*)d_in[0];
    const float* W1      = (const float*)d_in[1];
    const float* Wrec    = (const float*)d_in[2];
    const float* W2      = (const float*)d_in[3];
    const float* Wout    = (const float*)d_in[4];
    const float* alpha1  = (const float*)d_in[5];
    const float* rho1    = (const float*)d_in[6];
    const float* ba1     = (const float*)d_in[7];
    const float* alpha2  = (const float*)d_in[8];
    const float* rho2    = (const float*)d_in[9];
    const float* ba2     = (const float*)d_in[10];
    const float* beta_o  = (const float*)d_in[11];
    float* out = (float*)d_out;

    snn_main<<<dim3(Bv), dim3(512), 0, stream>>>(
        x, W1, Wrec, W2, Wout,
        alpha1, rho1, ba1, alpha2, rho2, ba2, beta_o, out);
}

// Round 8
// 105.876 us; speedup vs baseline: 1.3078x; 1.3078x over previous
//
#include <hip/hip_runtime.h>

#define Bv 256
#define Tv 200
#define Cv 40
#define H1v 512
#define H2v 256
#define Ov 12
#define THv 1.0f

typedef unsigned long long u64;
typedef _Float16 f16x2 __attribute__((ext_vector_type(2)));   // fdot2 operand type
typedef __fp16   g16x2 __attribute__((ext_vector_type(2)));   // cvt_pkrtz result type

#if defined(__has_builtin)
#if __has_builtin(__builtin_amdgcn_fdot2)
#define HAVE_FDOT2 1
#endif
#endif

// pack two fp32 -> u32 of two f16 (RTZ)
static __device__ __forceinline__ unsigned pkrtz(float a, float b) {
    union { g16x2 h; unsigned u; } cv;
    cv.h = __builtin_amdgcn_cvt_pkrtz(a, b);
    return cv.u;
}
static __device__ __forceinline__ f16x2 u2h(unsigned u) {
    union { unsigned u; f16x2 h; } cv; cv.u = u; return cv.h;
}
// c += dot(a,b) with fp32 accumulate
static __device__ __forceinline__ float dot2acc(unsigned a, unsigned b, float c) {
#ifdef HAVE_FDOT2
    return __builtin_amdgcn_fdot2(u2h(a), u2h(b), c, false);   // v_dot2_f32_f16
#else
    const f16x2 ah = u2h(a), bh = u2h(b);
    return c + (float)ah.x * (float)bh.x + (float)ah.y * (float)bh.y;
#endif
}

// ---------------------------------------------------------------------------
// One block per batch element, 512 threads (8 waves).
//
// PHASE 1 (speculative, barrier-free): waves 0-3 (256 threads), TWO hidden
// units per thread (tid, tid+256). R7 post-mortem: U=4 needs ~120 live VGPRs
// and hits the 128 allocator cap regardless of dtype -> spills, with 1
// wave/SIMD on only 2 SIMDs all latency exposed. U=2 needs ~90 VGPRs (40 for
// packed-f16 weights) -> no spill, and 4 waves use all 4 SIMDs. LDS cost:
// 4 waves x 5 ds_read_b128/step x 12cy = 240 cy/step (the floor, ~20us).
// Dots via v_dot2_f32_f16 (fp32 accumulate), x staged packed-f16 in LDS.
//
// Gate soundness for ANY input: per-dot error <= 40*xmax*wmax*2^-8 + 1e-5
// (covers RTZ input rounding, product, fp32 accum); EMA is convex, so
// |v_hat - v_exact| <= err. Fast path iff err < 0.25 && vmax < 1 - err;
// NaN/Inf fail the comparisons -> exact path. PHASE 2 = verbatim R1
// harness-verified fp32 kernel reading the untouched fp32 LDS copy.
// ---------------------------------------------------------------------------
__global__ __launch_bounds__(512) void snn_main(
    const float* __restrict__ x,
    const float* __restrict__ W1,
    const float* __restrict__ Wrec,
    const float* __restrict__ W2,
    const float* __restrict__ Wout,
    const float* __restrict__ alpha1, const float* __restrict__ rho1, const float* __restrict__ ba1,
    const float* __restrict__ alpha2, const float* __restrict__ rho2, const float* __restrict__ ba2,
    const float* __restrict__ beta_out,
    float* __restrict__ out)
{
    __shared__ __align__(16) float    lds_x [Tv * Cv];     // 32000 B fp32 (phase 2)
    __shared__ __align__(16) unsigned lds_xh[Tv * Cv / 2]; // 16000 B packed f16 (phase 1)
    __shared__ __align__(16) u64 s_m1[2][8];
    __shared__ __align__(16) u64 s_m2[2][4];
    __shared__ __align__(16) u64 s_red[8];
    __shared__ float s_xmax[8];

    const int b    = blockIdx.x;
    const int tid  = threadIdx.x;
    const int lane = tid & 63;
    const int wid  = tid >> 6;

    // --- stage x: fp32 copy + packed-f16 copy + block max|x| ---
    float xm = 0.f;
    {
        const float4* xg = (const float4*)(x + (size_t)b * (Tv * Cv));
        for (int i = tid; i < (Tv * Cv) / 4; i += 512) {
            const float4 v = xg[i];
            ((float4*)lds_x)[i] = v;
            uint2 pk;
            pk.x = pkrtz(v.x, v.y);
            pk.y = pkrtz(v.z, v.w);
            ((uint2*)lds_xh)[i] = pk;
            xm = fmaxf(xm, fmaxf(fmaxf(fabsf(v.x), fabsf(v.y)),
                                 fmaxf(fabsf(v.z), fabsf(v.w))));
        }
        #pragma unroll
        for (int o = 32; o > 0; o >>= 1) xm = fmaxf(xm, __shfl_xor(xm, o));
        if (lane == 0) s_xmax[wid] = xm;
    }
    __syncthreads();

    // ================= PHASE 1: 4-wave f16 speculative scan =================
    bool bad = false;
    if (tid < 256) {
        float xmax = s_xmax[0];
        #pragma unroll
        for (int i = 1; i < 8; ++i) xmax = fmaxf(xmax, s_xmax[i]);

        // 2 W1 rows -> packed f16 in 40 u32 regs; track max|w|
        unsigned w[2][20];
        float wmax = 0.f;
        #pragma unroll
        for (int u = 0; u < 2; ++u) {
            const float4* p = (const float4*)(W1 + (tid + 256 * u) * Cv);
            #pragma unroll
            for (int i = 0; i < 10; ++i) {
                const float4 q = p[i];
                wmax = fmaxf(wmax, fmaxf(fmaxf(fabsf(q.x), fabsf(q.y)),
                                         fmaxf(fabsf(q.z), fabsf(q.w))));
                w[u][2*i]   = pkrtz(q.x, q.y);
                w[u][2*i+1] = pkrtz(q.z, q.w);
            }
        }
        const float a0 = alpha1[tid],       k0 = 1.f - a0;
        const float a1 = alpha1[tid + 256], k1 = 1.f - a1;
        float v0 = 0.f, v1 = 0.f, vmax = 0.f;

        #pragma unroll 2
        for (int t = 0; t < Tv; ++t) {
            const uint4* xr = (const uint4*)(lds_xh + t * (Cv / 2)); // 80 B row
            const uint4 q0 = xr[0], q1 = xr[1], q2 = xr[2], q3 = xr[3], q4 = xr[4];
            const unsigned xq[20] = { q0.x, q0.y, q0.z, q0.w,
                                      q1.x, q1.y, q1.z, q1.w,
                                      q2.x, q2.y, q2.z, q2.w,
                                      q3.x, q3.y, q3.z, q3.w,
                                      q4.x, q4.y, q4.z, q4.w };
            float d0, d1;
            {
                float ce = 0.f, co = 0.f;
                #pragma unroll
                for (int i = 0; i < 20; i += 2) { ce = dot2acc(xq[i], w[0][i], ce); co = dot2acc(xq[i+1], w[0][i+1], co); }
                d0 = ce + co;
            }
            {
                float ce = 0.f, co = 0.f;
                #pragma unroll
                for (int i = 0; i < 20; i += 2) { ce = dot2acc(xq[i], w[1][i], ce); co = dot2acc(xq[i+1], w[1][i+1], co); }
                d1 = ce + co;
            }
            v0 = a0 * v0 + k0 * d0;
            v1 = a1 * v1 + k1 * d1;
            vmax = fmaxf(vmax, fmaxf(v0, v1));
        }

        // conservative f16 error bound; NaN/Inf fail the comparisons -> exact path
        const float err = 40.f * xmax * wmax * (1.f / 256.f) + 1e-5f;
        bad = !((err < 0.25f) && (vmax < 1.0f - err));
    }

    {
        const u64 bal = __ballot(bad);          // waves 4-7 contribute 0
        if (lane == 0) s_red[wid] = bal;
        __syncthreads();
        u64 any = 0ull;
        #pragma unroll
        for (int i = 0; i < 8; ++i) any |= s_red[i];
        if (any == 0ull) {
            // Provably spike-free: every downstream signal is exactly zero.
            if (tid < Ov) out[b * Ov + tid] = 0.f;
            return;
        }
    }

    // ================= PHASE 2: exact coupled simulation (rare) ===============
    // Verbatim R1 harness-verified pipelined kernel; fp32 lds_x untouched.
    float4 w1r[10];
    {
        const float4* p = (const float4*)(W1 + tid * Cv);
        #pragma unroll
        for (int i = 0; i < 10; ++i) w1r[i] = p[i];
    }
    const float al1 = alpha1[tid];
    const float rh1 = rho1[tid], bb1 = ba1[tid];
    float v1 = 0.f, a1 = 0.f, spk1 = 0.f;
    float al2 = 0.f, rh2 = 0.f, bb2 = 0.f, v2 = 0.f, a2 = 0.f;
    if (tid < H2v) { al2 = alpha2[tid]; rh2 = rho2[tid]; bb2 = ba2[tid]; }
    const float beta = beta_out[0];
    float vout = 0.f, osum = 0.f;

    if (tid < 8) { s_m1[0][tid] = 0ull; s_m1[1][tid] = 0ull; }
    if (tid < 4) { s_m2[0][tid] = 0ull; s_m2[1][tid] = 0ull; }
    __syncthreads();

    for (int t = 0; t < Tv + 2; ++t) {
        const int cur = t & 1, prev = cur ^ 1;

        u64 m1[8];
        #pragma unroll
        for (int i = 0; i < 8; ++i) m1[i] = s_m1[prev][i];
        u64 anyw = 0;
        #pragma unroll
        for (int i = 0; i < 8; ++i) anyw |= m1[i];
        const bool any1 = (anyw != 0ull);

        const bool doOut = (tid < Ov) & (t >= 2);
        u64 m2[4] = {0ull, 0ull, 0ull, 0ull};
        if (doOut) {
            #pragma unroll
            for (int i = 0; i < 4; ++i) m2[i] = s_m2[prev][i];
        }

        // ---- L1 update for step t ----
        if (t < Tv) {
            const float4* xr = (const float4*)(&lds_x[t * Cv]);
            float c0 = 0.f, c1 = 0.f, c2 = 0.f, c3 = 0.f;
            #pragma unroll
            for (int i = 0; i < 10; ++i) {
                const float4 xv = xr[i];
                c0 += xv.x * w1r[i].x;
                c1 += xv.y * w1r[i].y;
                c2 += xv.z * w1r[i].z;
                c3 += xv.w * w1r[i].w;
            }
            float acc = (c0 + c1) + (c2 + c3);
            if (any1) {
                #pragma unroll
                for (int w = 0; w < 8; ++w) {
                    u64 m = m1[w];
                    while (m) {
                        const int j = (w << 6) + __builtin_ctzll(m);
                        m &= (m - 1);
                        acc += Wrec[tid * H1v + j];
                    }
                }
            }
            v1 = al1 * (v1 - spk1 * THv) + (1.f - al1) * (acc - a1);
            const bool sp = (v1 >= THv);
            spk1 = sp ? 1.f : 0.f;
            a1 = rh1 * a1 + bb1 * spk1;
            const u64 bal = __ballot(sp);
            if (lane == 0) s_m1[cur][tid >> 6] = bal;
        }

        // ---- L2 update for step t-1 ----
        if ((tid < H2v) & (t >= 1) & (t <= Tv)) {
            float acc2 = 0.f;
            if (any1) {
                #pragma unroll
                for (int w = 0; w < 8; ++w) {
                    u64 m = m1[w];
                    while (m) {
                        const int j = (w << 6) + __builtin_ctzll(m);
                        m &= (m - 1);
                        acc2 += W2[tid * H1v + j];
                    }
                }
            }
            v2 = al2 * v2 + (1.f - al2) * (acc2 - a2);
            const bool sp2 = (v2 >= THv);
            a2 = rh2 * a2 + bb2 * (sp2 ? 1.f : 0.f);
            const u64 bal2 = __ballot(sp2);
            if (lane == 0) s_m2[cur][tid >> 6] = bal2;
        }

        // ---- Out update for step t-2 ----
        if (doOut) {
            float io = 0.f;
            if (m2[0] | m2[1] | m2[2] | m2[3]) {
                #pragma unroll
                for (int w = 0; w < 4; ++w) {
                    u64 m = m2[w];
                    while (m) {
                        const int j = (w << 6) + __builtin_ctzll(m);
                        m &= (m - 1);
                        io += Wout[tid * H2v + j];
                    }
                }
            }
            vout = beta * vout + (1.f - beta) * io;
            osum += vout;
        }

        __syncthreads();
    }

    if (tid < Ov) out[b * Ov + tid] = osum / (float)Tv;
}

extern "C" void kernel_launch(void* const* d_in, const int* in_sizes, int n_in,
                              void* d_out, int out_size, void* d_ws, size_t ws_size,
                              hipStream_t stream)
{
    const float* x       = (const float*)d_in[0];
    const float* W1      = (const float*)d_in[1];
    const float* Wrec    = (const float*)d_in[2];
    const float* W2      = (const float*)d_in[3];
    const float* Wout    = (const float*)d_in[4];
    const float* alpha1  = (const float*)d_in[5];
    const float* rho1    = (const float*)d_in[6];
    const float* ba1     = (const float*)d_in[7];
    const float* alpha2  = (const float*)d_in[8];
    const float* rho2    = (const float*)d_in[9];
    const float* ba2     = (const float*)d_in[10];
    const float* beta_o  = (const float*)d_in[11];
    float* out = (float*)d_out;

    snn_main<<<dim3(Bv), dim3(512), 0, stream>>>(
        x, W1, Wrec, W2, Wout,
        alpha1, rho1, ba1, alpha2, rho2, ba2, beta_o, out);
}